// Round 1
// baseline (1605.925 us; speedup 1.0000x reference)
//
#include <hip/hip_runtime.h>
#include <hip/hip_bf16.h>
#include <math.h>

#define NN 10000      // nodes
#define EE 320000     // edges
#define BB 8          // batch
#define SS 12         // seq
#define HH 64         // hidden
#define PP 3          // pred
#define LL 3          // layers
#define BN (BB*NN)    // 80000 rows

// ---------------- input projection: h[b,n,c] = sum_s x[b,s,n]*inW[s,c] + inb[c]
__global__ __launch_bounds__(256) void k_input_proj(const float* __restrict__ x,
                                                    const float* __restrict__ inW,
                                                    const float* __restrict__ inb,
                                                    float* __restrict__ h) {
    int idx = blockIdx.x * 256 + threadIdx.x;      // over BN*64
    if (idx >= BN * 64) return;
    int c  = idx & 63;
    int bn = idx >> 6;
    int n  = bn % NN;
    int b  = bn / NN;
    float s = inb[c];
#pragma unroll
    for (int t = 0; t < SS; ++t)
        s += x[(b * SS + t) * NN + n] * inW[t * 64 + c];
    h[idx] = s;
}

// ---------------- CSR build ----------------
__global__ __launch_bounds__(256) void k_count(const int* __restrict__ ei, int* __restrict__ cnt) {
    int e = blockIdx.x * 256 + threadIdx.x;
    if (e >= EE) return;
    atomicAdd(&cnt[ei[EE + e]], 1);   // dst
}

__global__ __launch_bounds__(1024) void k_scan(int* __restrict__ cnt, int* __restrict__ row_ptr) {
    __shared__ int sdata[1024];
    __shared__ int s_carry;
    int t = threadIdx.x;
    if (t == 0) s_carry = 0;
    __syncthreads();
    for (int base = 0; base < NN; base += 1024) {
        int i = base + t;
        int val = (i < NN) ? cnt[i] : 0;
        sdata[t] = val;
        __syncthreads();
        for (int off = 1; off < 1024; off <<= 1) {
            int tmp = (t >= off) ? sdata[t - off] : 0;
            __syncthreads();
            sdata[t] += tmp;
            __syncthreads();
        }
        int carry = s_carry;
        int excl = carry + sdata[t] - val;
        if (i < NN) { row_ptr[i] = excl; cnt[i] = excl; }  // cnt becomes cursor
        __syncthreads();
        if (t == 1023) s_carry = carry + sdata[1023];
        __syncthreads();
    }
    if (t == 0) row_ptr[NN] = s_carry;
}

__global__ __launch_bounds__(256) void k_fill(const int* __restrict__ ei, int* __restrict__ cursor,
                                              int* __restrict__ csr_src) {
    int e = blockIdx.x * 256 + threadIdx.x;
    if (e >= EE) return;
    int dst = ei[EE + e];
    int pos = atomicAdd(&cursor[dst], 1);
    csr_src[pos] = ei[e];   // src
}

// ---------------- K/V/SK gemm: per layer, rows = BN ----------------
// out: kbuf, vbuf, acc (acc gets the skip term h@Wsk+bsk)
__global__ __launch_bounds__(256) void k_qkvs(const float* __restrict__ h,
                                              const float* __restrict__ Wk, const float* __restrict__ bk,
                                              const float* __restrict__ Wv, const float* __restrict__ bv,
                                              const float* __restrict__ Ws, const float* __restrict__ bs,
                                              float* __restrict__ kbuf, float* __restrict__ vbuf,
                                              float* __restrict__ acc) {
    __shared__ float sW[3][64 * 64];   // 48 KB
    __shared__ float sh[64][64];       // 16 KB
    for (int i = threadIdx.x; i < 64 * 64; i += 256) {
        sW[0][i] = Wk[i]; sW[1][i] = Wv[i]; sW[2][i] = Ws[i];
    }
    int col  = threadIdx.x & 63;
    int rgrp = threadIdx.x >> 6;       // 0..3, wave-uniform
    float bkv = bk[col], bvv = bv[col], bsv = bs[col];
    __syncthreads();

    for (int tile = blockIdx.x; tile < BN / 64; tile += gridDim.x) {
        int row0 = tile * 64;
        const float4* hg = (const float4*)(h + row0 * 64);
        for (int i = threadIdx.x; i < 64 * 16; i += 256)
            ((float4*)&sh[0][0])[i] = hg[i];
        __syncthreads();

        float ak[16], av[16], as[16];
#pragma unroll
        for (int r = 0; r < 16; ++r) { ak[r] = bkv; av[r] = bvv; as[r] = bsv; }
        for (int i = 0; i < 64; ++i) {
            float wk = sW[0][i * 64 + col];
            float wv = sW[1][i * 64 + col];
            float ws = sW[2][i * 64 + col];
#pragma unroll
            for (int r = 0; r < 16; ++r) {
                float hv = sh[rgrp * 16 + r][i];
                ak[r] += hv * wk; av[r] += hv * wv; as[r] += hv * ws;
            }
        }
        __syncthreads();
#pragma unroll
        for (int r = 0; r < 16; ++r) {
            int row = row0 + rgrp * 16 + r;
            kbuf[row * 64 + col] = ak[r];
            vbuf[row * 64 + col] = av[r];
            acc [row * 64 + col] = as[r];
        }
    }
}

// ---------------- attention gather: one wave per (b,n) ----------------
__global__ __launch_bounds__(256) void k_attn(const float* __restrict__ h,
                                              const float* __restrict__ kbuf,
                                              const float* __restrict__ vbuf,
                                              const float* __restrict__ Wq, const float* __restrict__ bq,
                                              const int* __restrict__ row_ptr,
                                              const int* __restrict__ csr_src,
                                              float* __restrict__ acc) {
    __shared__ float sWq[64 * 64];
    for (int i = threadIdx.x; i < 4096; i += 256) sWq[i] = Wq[i];
    __syncthreads();

    int wid  = (blockIdx.x * 256 + threadIdx.x) >> 6;   // (b,n), grid sized exactly
    int lane = threadIdx.x & 63;
    int b = wid / NN, n = wid % NN;

    // q[lane] = bq[lane] + sum_i h[wid][i]*Wq[i][lane]
    float hv = h[wid * 64 + lane];
    float qv = bq[lane];
    for (int i = 0; i < 64; ++i)
        qv += __shfl(hv, i) * sWq[i * 64 + lane];

    int e0 = row_ptr[n], e1 = row_ptr[n + 1];
    int base = b * NN * 64;
    float m = -INFINITY, den = 0.f, avv = 0.f;
    for (int e = e0; e < e1; ++e) {
        int src = csr_src[e];
        float kv = kbuf[base + src * 64 + lane];
        float vv = vbuf[base + src * 64 + lane];
        float p = qv * kv;
        p += __shfl_xor(p, 1); p += __shfl_xor(p, 2);
        p += __shfl_xor(p, 4); p += __shfl_xor(p, 8);
        float logit = p * 0.25f;                       // /sqrt(16)
        if (logit <= m) {
            float w = __expf(logit - m);
            den += w; avv += w * vv;
        } else {
            float s = __expf(m - logit);
            den = den * s + 1.0f;
            avv = avv * s + vv;
            m = logit;
        }
    }
    float res = (den > 0.f) ? avv / den : 0.f;
    acc[wid * 64 + lane] += res;
}

// ---------------- residual + layernorm (in place on h) ----------------
__global__ __launch_bounds__(256) void k_ln(float* __restrict__ h, const float* __restrict__ acc,
                                            const float* __restrict__ g, const float* __restrict__ bta) {
    int wid  = (blockIdx.x * 256 + threadIdx.x) >> 6;
    int lane = threadIdx.x & 63;
    float x = h[wid * 64 + lane] + acc[wid * 64 + lane];
    float ssum = x;
#pragma unroll
    for (int off = 1; off < 64; off <<= 1) ssum += __shfl_xor(ssum, off);
    float mu = ssum * (1.f / 64.f);
    float d = x - mu;
    float vs = d * d;
#pragma unroll
    for (int off = 1; off < 64; off <<= 1) vs += __shfl_xor(vs, off);
    float r = rsqrtf(vs * (1.f / 64.f) + 1e-5f);
    h[wid * 64 + lane] = d * r * g[lane] + bta[lane];
}

// ---------------- output projection ----------------
__global__ __launch_bounds__(256) void k_out(const float* __restrict__ h,
                                             const float* __restrict__ W, const float* __restrict__ bo,
                                             float* __restrict__ out) {
    int idx = blockIdx.x * 256 + threadIdx.x;    // per (b,n)
    if (idx >= BN) return;
    int b = idx / NN, n = idx % NN;
    float a0 = bo[0], a1 = bo[1], a2 = bo[2];
    const float* hr = h + idx * 64;
#pragma unroll
    for (int i = 0; i < 64; ++i) {
        float hv = hr[i];
        a0 += hv * W[i * 3 + 0];
        a1 += hv * W[i * 3 + 1];
        a2 += hv * W[i * 3 + 2];
    }
    out[(b * PP + 0) * NN + n] = a0;
    out[(b * PP + 1) * NN + n] = a1;
    out[(b * PP + 2) * NN + n] = a2;
}

extern "C" void kernel_launch(void* const* d_in, const int* in_sizes, int n_in,
                              void* d_out, int out_size, void* d_ws, size_t ws_size,
                              hipStream_t stream) {
    const float* x    = (const float*)d_in[0];
    const int*   ei   = (const int*)  d_in[1];
    const float* inW  = (const float*)d_in[2];
    const float* inb  = (const float*)d_in[3];
    const float* Wq   = (const float*)d_in[4];
    const float* bq   = (const float*)d_in[5];
    const float* Wk   = (const float*)d_in[6];
    const float* bk   = (const float*)d_in[7];
    const float* Wv   = (const float*)d_in[8];
    const float* bv   = (const float*)d_in[9];
    const float* Wsk  = (const float*)d_in[10];
    const float* bsk  = (const float*)d_in[11];
    const float* lng  = (const float*)d_in[12];
    const float* lnb  = (const float*)d_in[13];
    const float* outW = (const float*)d_in[14];
    const float* outb = (const float*)d_in[15];
    float* out = (float*)d_out;

    float* h    = (float*)d_ws;
    float* kbuf = h    + (size_t)BN * 64;
    float* vbuf = kbuf + (size_t)BN * 64;
    float* acc  = vbuf + (size_t)BN * 64;
    int* row_ptr = (int*)(acc + (size_t)BN * 64);
    int* cursor  = row_ptr + (NN + 1);
    int* csr_src = cursor + NN;

    // CSR build (edge list constant across layers/batches)
    hipMemsetAsync(cursor, 0, NN * sizeof(int), stream);
    k_count<<<(EE + 255) / 256, 256, 0, stream>>>(ei, cursor);
    k_scan <<<1, 1024, 0, stream>>>(cursor, row_ptr);
    k_fill <<<(EE + 255) / 256, 256, 0, stream>>>(ei, cursor, csr_src);

    k_input_proj<<<(BN * 64 + 255) / 256, 256, 0, stream>>>(x, inW, inb, h);

    for (int l = 0; l < LL; ++l) {
        const float* Wq_l = Wq + (size_t)l * 64 * 64;  const float* bq_l = bq + (size_t)l * 64;
        const float* Wk_l = Wk + (size_t)l * 64 * 64;  const float* bk_l = bk + (size_t)l * 64;
        const float* Wv_l = Wv + (size_t)l * 64 * 64;  const float* bv_l = bv + (size_t)l * 64;
        const float* Ws_l = Wsk + (size_t)l * 64 * 64; const float* bs_l = bsk + (size_t)l * 64;

        k_qkvs<<<BN / 64, 256, 0, stream>>>(h, Wk_l, bk_l, Wv_l, bv_l, Ws_l, bs_l,
                                            kbuf, vbuf, acc);
        k_attn<<<BN / 4, 256, 0, stream>>>(h, kbuf, vbuf, Wq_l, bq_l, row_ptr, csr_src, acc);
        k_ln  <<<BN / 4, 256, 0, stream>>>(h, acc, lng, lnb);
    }

    k_out<<<(BN + 255) / 256, 256, 0, stream>>>(h, outW, outb, out);
}

// Round 2
// 557.110 us; speedup vs baseline: 2.8826x; 2.8826x over previous
//
#include <hip/hip_runtime.h>
#include <hip/hip_bf16.h>
#include <math.h>

#define NN 10000      // nodes
#define EE 320000     // edges
#define BB 8          // batch
#define SS 12         // seq
#define HH 64         // hidden
#define PP 3          // pred
#define LL 3          // layers
#define BN (BB*NN)    // 80000 rows

__device__ __forceinline__ float4 shfl_xor4(float4 v, int m) {
    float4 r;
    r.x = __shfl_xor(v.x, m); r.y = __shfl_xor(v.y, m);
    r.z = __shfl_xor(v.z, m); r.w = __shfl_xor(v.w, m);
    return r;
}

// ---------------- input projection: h[b,n,c] = sum_s x[b,s,n]*inW[s,c] + inb[c]
__global__ __launch_bounds__(256) void k_input_proj(const float* __restrict__ x,
                                                    const float* __restrict__ inW,
                                                    const float* __restrict__ inb,
                                                    float* __restrict__ h) {
    int idx = blockIdx.x * 256 + threadIdx.x;      // over BN*64
    if (idx >= BN * 64) return;
    int c  = idx & 63;
    int bn = idx >> 6;
    int n  = bn % NN;
    int b  = bn / NN;
    float s = inb[c];
#pragma unroll
    for (int t = 0; t < SS; ++t)
        s += x[(b * SS + t) * NN + n] * inW[t * 64 + c];
    h[idx] = s;
}

// ---------------- CSR build ----------------
__global__ __launch_bounds__(256) void k_count(const int* __restrict__ ei, int* __restrict__ cnt) {
    int e = blockIdx.x * 256 + threadIdx.x;
    if (e >= EE) return;
    atomicAdd(&cnt[ei[EE + e]], 1);   // dst
}

__global__ __launch_bounds__(1024) void k_scan(int* __restrict__ cnt, int* __restrict__ row_ptr) {
    __shared__ int sdata[1024];
    __shared__ int s_carry;
    int t = threadIdx.x;
    if (t == 0) s_carry = 0;
    __syncthreads();
    for (int base = 0; base < NN; base += 1024) {
        int i = base + t;
        int val = (i < NN) ? cnt[i] : 0;
        sdata[t] = val;
        __syncthreads();
        for (int off = 1; off < 1024; off <<= 1) {
            int tmp = (t >= off) ? sdata[t - off] : 0;
            __syncthreads();
            sdata[t] += tmp;
            __syncthreads();
        }
        int carry = s_carry;
        int excl = carry + sdata[t] - val;
        if (i < NN) { row_ptr[i] = excl; cnt[i] = excl; }  // cnt becomes cursor
        __syncthreads();
        if (t == 1023) s_carry = carry + sdata[1023];
        __syncthreads();
    }
    if (t == 0) row_ptr[NN] = s_carry;
}

__global__ __launch_bounds__(256) void k_fill(const int* __restrict__ ei, int* __restrict__ cursor,
                                              int* __restrict__ csr_src) {
    int e = blockIdx.x * 256 + threadIdx.x;
    if (e >= EE) return;
    int dst = ei[EE + e];
    int pos = atomicAdd(&cursor[dst], 1);
    csr_src[pos] = ei[e];   // src
}

// ---------------- Q/K/V/Skip gemm: 32-row tiles, 8 rows/thread ----------------
// writes qbuf (pre-scaled by 1/sqrt(C)), kbuf, vbuf, and h := h + h@Ws + bs
__global__ __launch_bounds__(256) void k_qkvs(float* __restrict__ h,
                                              const float* __restrict__ Wq, const float* __restrict__ bq,
                                              const float* __restrict__ Wk, const float* __restrict__ bk,
                                              const float* __restrict__ Wv, const float* __restrict__ bv,
                                              const float* __restrict__ Ws, const float* __restrict__ bs,
                                              float* __restrict__ qbuf, float* __restrict__ kbuf,
                                              float* __restrict__ vbuf) {
    __shared__ float sW[4][64 * 64];   // 64 KB
    __shared__ float sh[32][64];       // 8 KB
    for (int i = threadIdx.x; i < 64 * 64; i += 256) {
        sW[0][i] = Wq[i]; sW[1][i] = Wk[i]; sW[2][i] = Wv[i]; sW[3][i] = Ws[i];
    }
    int col = threadIdx.x & 63;
    int rg  = threadIdx.x >> 6;        // 0..3 -> rows rg*8..rg*8+7
    float bqv = bq[col], bkv = bk[col], bvv = bv[col], bsv = bs[col];
    __syncthreads();

    int row0 = blockIdx.x * 32;        // grid = BN/32 exactly
    const float4* hg = (const float4*)(h + (size_t)row0 * 64);
    for (int i = threadIdx.x; i < 32 * 16; i += 256)
        ((float4*)&sh[0][0])[i] = hg[i];
    __syncthreads();

    float aq[8], ak[8], av[8], as[8];
#pragma unroll
    for (int r = 0; r < 8; ++r) { aq[r] = bqv; ak[r] = bkv; av[r] = bvv; as[r] = bsv; }
    for (int i = 0; i < 64; ++i) {
        float wq = sW[0][i * 64 + col];
        float wk = sW[1][i * 64 + col];
        float wv = sW[2][i * 64 + col];
        float ws = sW[3][i * 64 + col];
#pragma unroll
        for (int r = 0; r < 8; ++r) {
            float hv = sh[rg * 8 + r][i];
            aq[r] += hv * wq; ak[r] += hv * wk; av[r] += hv * wv; as[r] += hv * ws;
        }
    }
#pragma unroll
    for (int r = 0; r < 8; ++r) {
        size_t row = (size_t)row0 + rg * 8 + r;
        qbuf[row * 64 + col] = aq[r] * 0.25f;   // fold 1/sqrt(16)
        kbuf[row * 64 + col] = ak[r];
        vbuf[row * 64 + col] = av[r];
        h   [row * 64 + col] = sh[rg * 8 + r][col] + as[r];  // residual base = h + skip
    }
}

// ---------------- fused attention gather + residual + layernorm ----------------
// one wave per (b,n); 4 lane-groups of 16 process 4 edges in parallel, float4/lane
__global__ __launch_bounds__(256) void k_attn_ln(const float* __restrict__ qbuf,
                                                 const float* __restrict__ kbuf,
                                                 const float* __restrict__ vbuf,
                                                 const int* __restrict__ row_ptr,
                                                 const int* __restrict__ csr_src,
                                                 const float* __restrict__ lng,
                                                 const float* __restrict__ lnb,
                                                 float* __restrict__ h) {
    int wid  = (blockIdx.x * 256 + threadIdx.x) >> 6;   // (b,n); grid sized exactly
    int lane = threadIdx.x & 63;
    int lg   = lane & 15;       // channel block: channels 4*lg..4*lg+3, head = lg>>2
    int grp  = lane >> 4;       // edge group 0..3
    int b = wid / NN, n = wid % NN;

    float4 q4 = ((const float4*)qbuf)[(size_t)wid * 16 + lg];

    int e0 = row_ptr[n], e1 = row_ptr[n + 1];
    size_t base4 = (size_t)b * NN * 16;                 // in float4 units
    float m = -1e30f, den = 0.f;
    float4 av = {0.f, 0.f, 0.f, 0.f};

    for (int e = e0; e < e1; e += 8) {
        int i0 = e + grp, i1 = e + 4 + grp;
        float val0 = (i0 < e1) ? 1.f : 0.f;
        float val1 = (i1 < e1) ? 1.f : 0.f;
        int c0 = min(i0, e1 - 1), c1 = min(i1, e1 - 1);
        int s0 = csr_src[c0], s1 = csr_src[c1];
        float4 ka = ((const float4*)kbuf)[base4 + (size_t)s0 * 16 + lg];
        float4 va = ((const float4*)vbuf)[base4 + (size_t)s0 * 16 + lg];
        float4 kb = ((const float4*)kbuf)[base4 + (size_t)s1 * 16 + lg];
        float4 vb = ((const float4*)vbuf)[base4 + (size_t)s1 * 16 + lg];

        float d0 = ka.x * q4.x + ka.y * q4.y + ka.z * q4.z + ka.w * q4.w;
        float d1 = kb.x * q4.x + kb.y * q4.y + kb.z * q4.z + kb.w * q4.w;
        d0 += __shfl_xor(d0, 1); d0 += __shfl_xor(d0, 2);   // head dot (16 lanes = 4x4)
        d1 += __shfl_xor(d1, 1); d1 += __shfl_xor(d1, 2);

        // branchless online softmax (exact for any max sequence; invalid -> w=0)
        float nm = fmaxf(m, d0);
        float sc = __expf(m - nm);
        float w  = val0 * __expf(d0 - nm);
        den = den * sc + w;
        av.x = av.x * sc + w * va.x; av.y = av.y * sc + w * va.y;
        av.z = av.z * sc + w * va.z; av.w = av.w * sc + w * va.w;
        m = nm;

        nm = fmaxf(m, d1);
        sc = __expf(m - nm);
        w  = val1 * __expf(d1 - nm);
        den = den * sc + w;
        av.x = av.x * sc + w * vb.x; av.y = av.y * sc + w * vb.y;
        av.z = av.z * sc + w * vb.z; av.w = av.w * sc + w * vb.w;
        m = nm;
    }

    // merge the 4 edge-groups (flash-style)
#pragma unroll
    for (int off = 16; off <= 32; off <<= 1) {
        float mo  = __shfl_xor(m, off);
        float dno = __shfl_xor(den, off);
        float4 ao = shfl_xor4(av, off);
        float nm = fmaxf(m, mo);
        float s0 = __expf(m - nm), s1 = __expf(mo - nm);
        den = den * s0 + dno * s1;
        av.x = av.x * s0 + ao.x * s1; av.y = av.y * s0 + ao.y * s1;
        av.z = av.z * s0 + ao.z * s1; av.w = av.w * s0 + ao.w * s1;
        m = nm;
    }
    float inv = (den > 0.f) ? 1.f / den : 0.f;

    // residual (h already holds h + skip) + layernorm
    float4 h4 = ((const float4*)h)[(size_t)wid * 16 + lg];
    float4 x4;
    x4.x = h4.x + av.x * inv; x4.y = h4.y + av.y * inv;
    x4.z = h4.z + av.z * inv; x4.w = h4.w + av.w * inv;

    float s = x4.x + x4.y + x4.z + x4.w;
#pragma unroll
    for (int off = 1; off < 16; off <<= 1) s += __shfl_xor(s, off);
    float mu = s * (1.f / 64.f);
    float4 dx;
    dx.x = x4.x - mu; dx.y = x4.y - mu; dx.z = x4.z - mu; dx.w = x4.w - mu;
    float vs = dx.x * dx.x + dx.y * dx.y + dx.z * dx.z + dx.w * dx.w;
#pragma unroll
    for (int off = 1; off < 16; off <<= 1) vs += __shfl_xor(vs, off);
    float r = rsqrtf(vs * (1.f / 64.f) + 1e-5f);

    float4 g4 = ((const float4*)lng)[lg];
    float4 b4 = ((const float4*)lnb)[lg];
    float4 o4;
    o4.x = dx.x * r * g4.x + b4.x; o4.y = dx.y * r * g4.y + b4.y;
    o4.z = dx.z * r * g4.z + b4.z; o4.w = dx.w * r * g4.w + b4.w;
    if (lane < 16)
        ((float4*)h)[(size_t)wid * 16 + lg] = o4;
}

// ---------------- output projection ----------------
__global__ __launch_bounds__(256) void k_out(const float* __restrict__ h,
                                             const float* __restrict__ W, const float* __restrict__ bo,
                                             float* __restrict__ out) {
    int idx = blockIdx.x * 256 + threadIdx.x;    // per (b,n)
    if (idx >= BN) return;
    int b = idx / NN, n = idx % NN;
    float a0 = bo[0], a1 = bo[1], a2 = bo[2];
    const float* hr = h + (size_t)idx * 64;
#pragma unroll
    for (int i = 0; i < 64; ++i) {
        float hv = hr[i];
        a0 += hv * W[i * 3 + 0];
        a1 += hv * W[i * 3 + 1];
        a2 += hv * W[i * 3 + 2];
    }
    out[(b * PP + 0) * NN + n] = a0;
    out[(b * PP + 1) * NN + n] = a1;
    out[(b * PP + 2) * NN + n] = a2;
}

extern "C" void kernel_launch(void* const* d_in, const int* in_sizes, int n_in,
                              void* d_out, int out_size, void* d_ws, size_t ws_size,
                              hipStream_t stream) {
    const float* x    = (const float*)d_in[0];
    const int*   ei   = (const int*)  d_in[1];
    const float* inW  = (const float*)d_in[2];
    const float* inb  = (const float*)d_in[3];
    const float* Wq   = (const float*)d_in[4];
    const float* bq   = (const float*)d_in[5];
    const float* Wk   = (const float*)d_in[6];
    const float* bk   = (const float*)d_in[7];
    const float* Wv   = (const float*)d_in[8];
    const float* bv   = (const float*)d_in[9];
    const float* Wsk  = (const float*)d_in[10];
    const float* bsk  = (const float*)d_in[11];
    const float* lng  = (const float*)d_in[12];
    const float* lnb  = (const float*)d_in[13];
    const float* outW = (const float*)d_in[14];
    const float* outb = (const float*)d_in[15];
    float* out = (float*)d_out;

    float* h    = (float*)d_ws;
    float* kbuf = h    + (size_t)BN * 64;
    float* vbuf = kbuf + (size_t)BN * 64;
    float* qbuf = vbuf + (size_t)BN * 64;
    int* row_ptr = (int*)(qbuf + (size_t)BN * 64);
    int* cursor  = row_ptr + (NN + 1);
    int* csr_src = cursor + NN;

    // CSR build (edge list constant across layers/batches)
    hipMemsetAsync(cursor, 0, NN * sizeof(int), stream);
    k_count<<<(EE + 255) / 256, 256, 0, stream>>>(ei, cursor);
    k_scan <<<1, 1024, 0, stream>>>(cursor, row_ptr);
    k_fill <<<(EE + 255) / 256, 256, 0, stream>>>(ei, cursor, csr_src);

    k_input_proj<<<(BN * 64 + 255) / 256, 256, 0, stream>>>(x, inW, inb, h);

    for (int l = 0; l < LL; ++l) {
        const size_t wo = (size_t)l * 64 * 64, bo_ = (size_t)l * 64;
        k_qkvs<<<BN / 32, 256, 0, stream>>>(h, Wq + wo, bq + bo_, Wk + wo, bk + bo_,
                                            Wv + wo, bv + bo_, Wsk + wo, bsk + bo_,
                                            qbuf, kbuf, vbuf);
        k_attn_ln<<<BN / 4, 256, 0, stream>>>(qbuf, kbuf, vbuf, row_ptr, csr_src,
                                              lng, lnb, h);
    }

    k_out<<<(BN + 255) / 256, 256, 0, stream>>>(h, outW, outb, out);
}

// Round 3
// 536.283 us; speedup vs baseline: 2.9945x; 1.0388x over previous
//
#include <hip/hip_runtime.h>
#include <hip/hip_bf16.h>
#include <math.h>

#define NN 10000      // nodes
#define EE 320000     // edges
#define BB 8          // batch
#define SS 12         // seq
#define PP 3          // pred
#define LL 3          // layers
#define BN (BB*NN)    // 80000 rows
#define QSCL (0.25f * 1.44269504f)   // 1/sqrt(16) * log2(e)  -> exp2 domain

typedef __attribute__((ext_vector_type(8))) short bf8_t;   // 8 bf16 (4 VGPR)
typedef __attribute__((ext_vector_type(4))) float f4_t;

__device__ __forceinline__ float bf2f(unsigned short u) {
    unsigned int x = ((unsigned int)u) << 16;
    return __builtin_bit_cast(float, x);
}
__device__ __forceinline__ unsigned short f2bf(float f) {
    unsigned int u = __builtin_bit_cast(unsigned int, f);
    u += 0x7FFF + ((u >> 16) & 1);           // RNE
    return (unsigned short)(u >> 16);
}
__device__ __forceinline__ float4 shfl_xor4(float4 v, int m) {
    float4 r;
    r.x = __shfl_xor(v.x, m); r.y = __shfl_xor(v.y, m);
    r.z = __shfl_xor(v.z, m); r.w = __shfl_xor(v.w, m);
    return r;
}

// ---------------- input projection (+ bf16 shadow) ----------------
__global__ __launch_bounds__(256) void k_input_proj(const float* __restrict__ x,
                                                    const float* __restrict__ inW,
                                                    const float* __restrict__ inb,
                                                    float* __restrict__ h,
                                                    unsigned short* __restrict__ hb) {
    int idx = blockIdx.x * 256 + threadIdx.x;      // over BN*64
    if (idx >= BN * 64) return;
    int c  = idx & 63;
    int bn = idx >> 6;
    int n  = bn % NN;
    int b  = bn / NN;
    float s = inb[c];
#pragma unroll
    for (int t = 0; t < SS; ++t)
        s += x[(b * SS + t) * NN + n] * inW[t * 64 + c];
    h[idx]  = s;
    hb[idx] = f2bf(s);
}

// ---------------- CSR build ----------------
__global__ __launch_bounds__(256) void k_count(const int* __restrict__ ei, int* __restrict__ cnt) {
    int e = blockIdx.x * 256 + threadIdx.x;
    if (e >= EE) return;
    atomicAdd(&cnt[ei[EE + e]], 1);   // dst
}

__global__ __launch_bounds__(1024) void k_scan(int* __restrict__ cnt, int* __restrict__ row_ptr) {
    __shared__ int sdata[1024];
    __shared__ int s_carry;
    int t = threadIdx.x;
    if (t == 0) s_carry = 0;
    __syncthreads();
    for (int base = 0; base < NN; base += 1024) {
        int i = base + t;
        int val = (i < NN) ? cnt[i] : 0;
        sdata[t] = val;
        __syncthreads();
        for (int off = 1; off < 1024; off <<= 1) {
            int tmp = (t >= off) ? sdata[t - off] : 0;
            __syncthreads();
            sdata[t] += tmp;
            __syncthreads();
        }
        int carry = s_carry;
        int excl = carry + sdata[t] - val;
        if (i < NN) { row_ptr[i] = excl; cnt[i] = excl; }  // cnt becomes cursor
        __syncthreads();
        if (t == 1023) s_carry = carry + sdata[1023];
        __syncthreads();
    }
    if (t == 0) row_ptr[NN] = s_carry;
}

__global__ __launch_bounds__(256) void k_fill(const int* __restrict__ ei, int* __restrict__ cursor,
                                              int* __restrict__ csr_src) {
    int e = blockIdx.x * 256 + threadIdx.x;
    if (e >= EE) return;
    int dst = ei[EE + e];
    int pos = atomicAdd(&cursor[dst], 1);
    csr_src[pos] = ei[e];   // src
}

// ---------------- weight prep: bf16, transposed [col][k]; q pre-scaled ----------------
__global__ __launch_bounds__(256) void k_wprep(const float* __restrict__ Wq, const float* __restrict__ Wk,
                                               const float* __restrict__ Wv, const float* __restrict__ Ws,
                                               const float* __restrict__ bq, const float* __restrict__ bk,
                                               const float* __restrict__ bv, const float* __restrict__ bs,
                                               unsigned short* __restrict__ wtb, float* __restrict__ bprep) {
    int idx = blockIdx.x * 256 + threadIdx.x;
    if (idx < LL * 4 * 64 * 64) {
        int l = idx >> 14; int j = (idx >> 12) & 3; int col = (idx >> 6) & 63; int k = idx & 63;
        const float* W = (j == 0 ? Wq : j == 1 ? Wk : j == 2 ? Wv : Ws) + l * 4096;
        float v = W[k * 64 + col];
        if (j == 0) v *= QSCL;
        wtb[idx] = f2bf(v);
    }
    if (idx < LL * 4 * 64) {
        int l = idx >> 8; int j = (idx >> 6) & 3; int c = idx & 63;
        const float* bsrc = (j == 0 ? bq : j == 1 ? bk : j == 2 ? bv : bs) + l * 64;
        bprep[idx] = bsrc[c] * (j == 0 ? QSCL : 1.0f);
    }
}

// ---------------- MFMA GEMM: one block per 64-row tile; wave w = matrix w ----------------
// w=0: qb (bf16, pre-scaled), w=1: kbuf, w=2: vbuf, w=3: h += skip
__global__ __launch_bounds__(256) void k_gemm(const unsigned short* __restrict__ hb,
                                              float* __restrict__ h,
                                              const unsigned short* __restrict__ wtb,   // + layer off
                                              const float* __restrict__ bprep,          // + layer off
                                              unsigned short* __restrict__ qb,
                                              float* __restrict__ kbuf, float* __restrict__ vbuf) {
    int tid = threadIdx.x;
    int l = tid & 63, w = tid >> 6;
    int row0 = blockIdx.x * 64;
    int colb = l & 15, kg = l >> 4;

    const unsigned short* wb = wtb + (size_t)w * 4096;   // [col][k]
    bf8_t bfr[2][4];
#pragma unroll
    for (int ks = 0; ks < 2; ++ks)
#pragma unroll
        for (int ct = 0; ct < 4; ++ct)
            bfr[ks][ct] = *(const bf8_t*)(wb + (ct * 16 + colb) * 64 + ks * 32 + kg * 8);

    bf8_t afr[2][4];
#pragma unroll
    for (int ks = 0; ks < 2; ++ks)
#pragma unroll
        for (int rt = 0; rt < 4; ++rt)
            afr[ks][rt] = *(const bf8_t*)(hb + (size_t)(row0 + rt * 16 + colb) * 64 + ks * 32 + kg * 8);

    f4_t acc[4][4];
#pragma unroll
    for (int rt = 0; rt < 4; ++rt)
#pragma unroll
        for (int ct = 0; ct < 4; ++ct)
            acc[rt][ct] = (f4_t){0.f, 0.f, 0.f, 0.f};
#pragma unroll
    for (int ks = 0; ks < 2; ++ks)
#pragma unroll
        for (int rt = 0; rt < 4; ++rt)
#pragma unroll
            for (int ct = 0; ct < 4; ++ct)
                acc[rt][ct] = __builtin_amdgcn_mfma_f32_16x16x32_bf16(afr[ks][rt], bfr[ks][ct],
                                                                      acc[rt][ct], 0, 0, 0);
    int rquad = l >> 4;     // D: col = l&15, row = rquad*4 + reg
#pragma unroll
    for (int ct = 0; ct < 4; ++ct) {
        int col = ct * 16 + colb;
        float bias = bprep[w * 64 + col];
#pragma unroll
        for (int rt = 0; rt < 4; ++rt)
#pragma unroll
            for (int r = 0; r < 4; ++r) {
                int row = row0 + rt * 16 + rquad * 4 + r;
                float val = acc[rt][ct][r] + bias;
                size_t off = (size_t)row * 64 + col;
                if      (w == 0) qb[off] = f2bf(val);
                else if (w == 1) kbuf[off] = val;
                else if (w == 2) vbuf[off] = val;
                else             h[off] += val;     // residual base = h + skip
            }
    }
}

// ---------------- fused attention gather + residual + layernorm ----------------
__global__ __launch_bounds__(256) void k_attn_ln(const unsigned short* __restrict__ qb,
                                                 const float* __restrict__ kbuf,
                                                 const float* __restrict__ vbuf,
                                                 const int* __restrict__ row_ptr,
                                                 const int* __restrict__ csr_src,
                                                 const float* __restrict__ lng,
                                                 const float* __restrict__ lnb,
                                                 float* __restrict__ h,
                                                 unsigned short* __restrict__ hb) {
    int wid  = (blockIdx.x * 256 + threadIdx.x) >> 6;   // (b,n); grid sized exactly
    int lane = threadIdx.x & 63;
    int lg   = lane & 15;       // channel block: channels 4*lg..4*lg+3, head = lg>>2
    int grp  = lane >> 4;       // edge group 0..3
    int b = wid / NN, n = wid % NN;

    ushort4 qu = ((const ushort4*)qb)[(size_t)wid * 16 + lg];
    float4 q4 = {bf2f(qu.x), bf2f(qu.y), bf2f(qu.z), bf2f(qu.w)};   // already *0.25*log2e

    int e0 = row_ptr[n], e1 = row_ptr[n + 1];
    size_t base4 = (size_t)b * NN * 16;                 // in float4 units
    float m = -1e30f, den = 0.f;
    float4 av = {0.f, 0.f, 0.f, 0.f};

    for (int e = e0; e < e1; e += 8) {
        int i0 = e + grp, i1 = i0 + 4;
        float val0 = (i0 < e1) ? 1.f : 0.f;
        float val1 = (i1 < e1) ? 1.f : 0.f;
        int c0 = min(i0, e1 - 1), c1 = min(i1, e1 - 1);
        int s0 = csr_src[c0], s1 = csr_src[c1];
        float4 ka = ((const float4*)kbuf)[base4 + (size_t)s0 * 16 + lg];
        float4 va = ((const float4*)vbuf)[base4 + (size_t)s0 * 16 + lg];
        float4 kb = ((const float4*)kbuf)[base4 + (size_t)s1 * 16 + lg];
        float4 vb = ((const float4*)vbuf)[base4 + (size_t)s1 * 16 + lg];

        float d0 = ka.x * q4.x + ka.y * q4.y + ka.z * q4.z + ka.w * q4.w;
        float d1 = kb.x * q4.x + kb.y * q4.y + kb.z * q4.z + kb.w * q4.w;
        d0 += __shfl_xor(d0, 1); d0 += __shfl_xor(d0, 2);   // per-head dot (log2 domain)
        d1 += __shfl_xor(d1, 1); d1 += __shfl_xor(d1, 2);

        float dm = fmaxf(d0, d1);
        if (__any(dm > m)) {
            // exact two-step online update (rare path)
            float nm = fmaxf(m, d0);
            float sc = exp2f(m - nm);
            float w0 = val0 * exp2f(d0 - nm);
            den = den * sc + w0;
            av.x = av.x * sc + w0 * va.x; av.y = av.y * sc + w0 * va.y;
            av.z = av.z * sc + w0 * va.z; av.w = av.w * sc + w0 * va.w;
            m = nm;
            nm = fmaxf(m, d1);
            sc = exp2f(m - nm);
            float w1 = val1 * exp2f(d1 - nm);
            den = den * sc + w1;
            av.x = av.x * sc + w1 * vb.x; av.y = av.y * sc + w1 * vb.y;
            av.z = av.z * sc + w1 * vb.z; av.w = av.w * sc + w1 * vb.w;
            m = nm;
        } else {
            // fast path: max unchanged, no rescale
            float w0 = val0 * exp2f(d0 - m);
            float w1 = val1 * exp2f(d1 - m);
            den += w0 + w1;
            av.x += w0 * va.x + w1 * vb.x; av.y += w0 * va.y + w1 * vb.y;
            av.z += w0 * va.z + w1 * vb.z; av.w += w0 * va.w + w1 * vb.w;
        }
    }

    // merge the 4 edge-groups (flash-style)
#pragma unroll
    for (int off = 16; off <= 32; off <<= 1) {
        float mo  = __shfl_xor(m, off);
        float dno = __shfl_xor(den, off);
        float4 ao = shfl_xor4(av, off);
        float nm = fmaxf(m, mo);
        float s0 = exp2f(m - nm), s1 = exp2f(mo - nm);
        den = den * s0 + dno * s1;
        av.x = av.x * s0 + ao.x * s1; av.y = av.y * s0 + ao.y * s1;
        av.z = av.z * s0 + ao.z * s1; av.w = av.w * s0 + ao.w * s1;
        m = nm;
    }
    float inv = (den > 0.f) ? 1.f / den : 0.f;

    // residual (h already holds h + skip) + layernorm
    float4 h4 = ((const float4*)h)[(size_t)wid * 16 + lg];
    float4 x4;
    x4.x = h4.x + av.x * inv; x4.y = h4.y + av.y * inv;
    x4.z = h4.z + av.z * inv; x4.w = h4.w + av.w * inv;

    float s = x4.x + x4.y + x4.z + x4.w;
#pragma unroll
    for (int off = 1; off < 16; off <<= 1) s += __shfl_xor(s, off);
    float mu = s * (1.f / 64.f);
    float4 dx;
    dx.x = x4.x - mu; dx.y = x4.y - mu; dx.z = x4.z - mu; dx.w = x4.w - mu;
    float vs = dx.x * dx.x + dx.y * dx.y + dx.z * dx.z + dx.w * dx.w;
#pragma unroll
    for (int off = 1; off < 16; off <<= 1) vs += __shfl_xor(vs, off);
    float r = rsqrtf(vs * (1.f / 64.f) + 1e-5f);

    float4 g4 = ((const float4*)lng)[lg];
    float4 b4 = ((const float4*)lnb)[lg];
    float4 o4;
    o4.x = dx.x * r * g4.x + b4.x; o4.y = dx.y * r * g4.y + b4.y;
    o4.z = dx.z * r * g4.z + b4.z; o4.w = dx.w * r * g4.w + b4.w;
    if (lane < 16) {
        ((float4*)h)[(size_t)wid * 16 + lg] = o4;
        ushort4 hu = {f2bf(o4.x), f2bf(o4.y), f2bf(o4.z), f2bf(o4.w)};
        ((ushort4*)hb)[(size_t)wid * 16 + lg] = hu;
    }
}

// ---------------- output projection ----------------
__global__ __launch_bounds__(256) void k_out(const float* __restrict__ h,
                                             const float* __restrict__ W, const float* __restrict__ bo,
                                             float* __restrict__ out) {
    int idx = blockIdx.x * 256 + threadIdx.x;    // per (b,n)
    if (idx >= BN) return;
    int b = idx / NN, n = idx % NN;
    float a0 = bo[0], a1 = bo[1], a2 = bo[2];
    const float* hr = h + (size_t)idx * 64;
#pragma unroll
    for (int i = 0; i < 64; ++i) {
        float hv = hr[i];
        a0 += hv * W[i * 3 + 0];
        a1 += hv * W[i * 3 + 1];
        a2 += hv * W[i * 3 + 2];
    }
    out[(b * PP + 0) * NN + n] = a0;
    out[(b * PP + 1) * NN + n] = a1;
    out[(b * PP + 2) * NN + n] = a2;
}

extern "C" void kernel_launch(void* const* d_in, const int* in_sizes, int n_in,
                              void* d_out, int out_size, void* d_ws, size_t ws_size,
                              hipStream_t stream) {
    const float* x    = (const float*)d_in[0];
    const int*   ei   = (const int*)  d_in[1];
    const float* inW  = (const float*)d_in[2];
    const float* inb  = (const float*)d_in[3];
    const float* Wq   = (const float*)d_in[4];
    const float* bq   = (const float*)d_in[5];
    const float* Wk   = (const float*)d_in[6];
    const float* bk   = (const float*)d_in[7];
    const float* Wv   = (const float*)d_in[8];
    const float* bv   = (const float*)d_in[9];
    const float* Wsk  = (const float*)d_in[10];
    const float* bsk  = (const float*)d_in[11];
    const float* lng  = (const float*)d_in[12];
    const float* lnb  = (const float*)d_in[13];
    const float* outW = (const float*)d_in[14];
    const float* outb = (const float*)d_in[15];
    float* out = (float*)d_out;

    float* h    = (float*)d_ws;                         // BN*64 f32
    float* kbuf = h    + (size_t)BN * 64;
    float* vbuf = kbuf + (size_t)BN * 64;
    unsigned short* hb = (unsigned short*)(vbuf + (size_t)BN * 64);   // BN*64 bf16
    unsigned short* qb = hb + (size_t)BN * 64;                        // BN*64 bf16
    int* row_ptr = (int*)(qb + (size_t)BN * 64);
    int* cursor  = row_ptr + (NN + 1);
    int* csr_src = cursor + NN;
    unsigned short* wtb = (unsigned short*)(csr_src + EE);  // LL*4*64*64 bf16
    float* bprep = (float*)(wtb + LL * 4 * 64 * 64);        // LL*4*64 f32

    // CSR build + weight prep (edge list/weights constant across layers/batches)
    hipMemsetAsync(cursor, 0, NN * sizeof(int), stream);
    k_count<<<(EE + 255) / 256, 256, 0, stream>>>(ei, cursor);
    k_scan <<<1, 1024, 0, stream>>>(cursor, row_ptr);
    k_fill <<<(EE + 255) / 256, 256, 0, stream>>>(ei, cursor, csr_src);
    k_wprep<<<(LL * 4 * 64 * 64 + 255) / 256, 256, 0, stream>>>(Wq, Wk, Wv, Wsk, bq, bk, bv, bsk,
                                                                wtb, bprep);

    k_input_proj<<<(BN * 64 + 255) / 256, 256, 0, stream>>>(x, inW, inb, h, hb);

    for (int l = 0; l < LL; ++l) {
        k_gemm<<<BN / 64, 256, 0, stream>>>(hb, h, wtb + (size_t)l * 4 * 4096,
                                            bprep + (size_t)l * 4 * 64, qb, kbuf, vbuf);
        k_attn_ln<<<BN / 4, 256, 0, stream>>>(qb, kbuf, vbuf, row_ptr, csr_src,
                                              lng, lnb, h, hb);
    }

    k_out<<<(BN + 255) / 256, 256, 0, stream>>>(h, outW, outb, out);
}

// Round 4
// 446.792 us; speedup vs baseline: 3.5943x; 1.2003x over previous
//
#include <hip/hip_runtime.h>
#include <hip/hip_bf16.h>
#include <math.h>

#define NN 10000      // nodes
#define EE 320000     // edges
#define BB 8          // batch
#define SS 12         // seq
#define PP 3          // pred
#define LL 3          // layers
#define BN (BB*NN)    // 80000 rows
#define CSR_CAP (EE + 8*NN + 16)     // padded-to-8 lists + prefetch slack
#define QSCL (0.25f * 1.44269504f)   // 1/sqrt(16) * log2(e)  -> exp2 domain

typedef __attribute__((ext_vector_type(8))) short bf8_t;   // 8 bf16 (4 VGPR)
typedef __attribute__((ext_vector_type(4))) float f4_t;

__device__ __forceinline__ float bf2f(unsigned short u) {
    unsigned int x = ((unsigned int)u) << 16;
    return __builtin_bit_cast(float, x);
}
__device__ __forceinline__ unsigned short f2bf(float f) {
    unsigned int u = __builtin_bit_cast(unsigned int, f);
    u += 0x7FFF + ((u >> 16) & 1);           // RNE
    return (unsigned short)(u >> 16);
}
__device__ __forceinline__ float4 shfl_xor4(float4 v, int m) {
    float4 r;
    r.x = __shfl_xor(v.x, m); r.y = __shfl_xor(v.y, m);
    r.z = __shfl_xor(v.z, m); r.w = __shfl_xor(v.w, m);
    return r;
}

// ---------------- input projection (+ bf16 shadow) ----------------
__global__ __launch_bounds__(256) void k_input_proj(const float* __restrict__ x,
                                                    const float* __restrict__ inW,
                                                    const float* __restrict__ inb,
                                                    float* __restrict__ h,
                                                    unsigned short* __restrict__ hb) {
    int idx = blockIdx.x * 256 + threadIdx.x;      // over BN*64
    if (idx >= BN * 64) return;
    int c  = idx & 63;
    int bn = idx >> 6;
    int n  = bn % NN;
    int b  = bn / NN;
    float s = inb[c];
#pragma unroll
    for (int t = 0; t < SS; ++t)
        s += x[(b * SS + t) * NN + n] * inW[t * 64 + c];
    h[idx]  = s;
    hb[idx] = f2bf(s);
}

// ---------------- CSR build ----------------
__global__ __launch_bounds__(256) void k_count(const int* __restrict__ ei, int* __restrict__ cnt) {
    int e = blockIdx.x * 256 + threadIdx.x;
    if (e >= EE) return;
    atomicAdd(&cnt[ei[EE + e]], 1);   // dst
}

// single block, 1024 threads, 10 nodes/thread serial + one block scan.
// outputs: rp[n] = padded start, degv[n] = real degree, cursor[n] = rp[n]
__global__ __launch_bounds__(1024) void k_scan(int* __restrict__ cnt,      // in: counts (== cursor buf)
                                               int* __restrict__ rp,
                                               int* __restrict__ degv) {
    __shared__ int ssum[1024];
    int t = threadIdx.x;
    int base = t * 10;
    int loc[10];
    int s = 0;
#pragma unroll
    for (int j = 0; j < 10; ++j) {
        int i = base + j;
        int d = (i < NN) ? cnt[i] : 0;
        loc[j] = d;
        s += (d + 7) & ~7;
    }
    ssum[t] = s;
    __syncthreads();
    for (int off = 1; off < 1024; off <<= 1) {
        int v = (t >= off) ? ssum[t - off] : 0;
        __syncthreads();
        ssum[t] += v;
        __syncthreads();
    }
    int run = ssum[t] - s;   // exclusive prefix of padded sizes
#pragma unroll
    for (int j = 0; j < 10; ++j) {
        int i = base + j;
        if (i < NN) {
            rp[i]   = run;
            degv[i] = loc[j];
            cnt[i]  = run;           // cursor for fill
            run += (loc[j] + 7) & ~7;
        }
    }
}

__global__ __launch_bounds__(256) void k_fill(const int* __restrict__ ei, int* __restrict__ cursor,
                                              int* __restrict__ csr) {
    int e = blockIdx.x * 256 + threadIdx.x;
    if (e >= EE) return;
    int dst = ei[EE + e];
    int pos = atomicAdd(&cursor[dst], 1);
    csr[pos] = ei[e] << 8;            // byte offset of 256B f32 row
}

// ---------------- weight prep: bf16, transposed [col][k]; q pre-scaled ----------------
__global__ __launch_bounds__(256) void k_wprep(const float* __restrict__ Wq, const float* __restrict__ Wk,
                                               const float* __restrict__ Wv, const float* __restrict__ Ws,
                                               const float* __restrict__ bq, const float* __restrict__ bk,
                                               const float* __restrict__ bv, const float* __restrict__ bs,
                                               unsigned short* __restrict__ wtb, float* __restrict__ bprep) {
    int idx = blockIdx.x * 256 + threadIdx.x;
    if (idx < LL * 4 * 64 * 64) {
        int l = idx >> 14; int j = (idx >> 12) & 3; int col = (idx >> 6) & 63; int k = idx & 63;
        const float* W = (j == 0 ? Wq : j == 1 ? Wk : j == 2 ? Wv : Ws) + l * 4096;
        float v = W[k * 64 + col];
        if (j == 0) v *= QSCL;
        wtb[idx] = f2bf(v);
    }
    if (idx < LL * 4 * 64) {
        int l = idx >> 8; int j = (idx >> 6) & 3; int c = idx & 63;
        const float* bsrc = (j == 0 ? bq : j == 1 ? bk : j == 2 ? bv : bs) + l * 64;
        bprep[idx] = bsrc[c] * (j == 0 ? QSCL : 1.0f);
    }
}

// ---------------- MFMA GEMM: one block per 64-row tile; wave w = matrix w ----------------
// w=0: qb (bf16, pre-scaled), w=1: kbuf, w=2: vbuf, w=3: h += skip
__global__ __launch_bounds__(256) void k_gemm(const unsigned short* __restrict__ hb,
                                              float* __restrict__ h,
                                              const unsigned short* __restrict__ wtb,   // + layer off
                                              const float* __restrict__ bprep,          // + layer off
                                              unsigned short* __restrict__ qb,
                                              float* __restrict__ kbuf, float* __restrict__ vbuf) {
    int tid = threadIdx.x;
    int l = tid & 63, w = tid >> 6;
    int row0 = blockIdx.x * 64;
    int colb = l & 15, kg = l >> 4;

    const unsigned short* wb = wtb + (size_t)w * 4096;   // [col][k]
    bf8_t bfr[2][4];
#pragma unroll
    for (int ks = 0; ks < 2; ++ks)
#pragma unroll
        for (int ct = 0; ct < 4; ++ct)
            bfr[ks][ct] = *(const bf8_t*)(wb + (ct * 16 + colb) * 64 + ks * 32 + kg * 8);

    bf8_t afr[2][4];
#pragma unroll
    for (int ks = 0; ks < 2; ++ks)
#pragma unroll
        for (int rt = 0; rt < 4; ++rt)
            afr[ks][rt] = *(const bf8_t*)(hb + (size_t)(row0 + rt * 16 + colb) * 64 + ks * 32 + kg * 8);

    f4_t acc[4][4];
#pragma unroll
    for (int rt = 0; rt < 4; ++rt)
#pragma unroll
        for (int ct = 0; ct < 4; ++ct)
            acc[rt][ct] = (f4_t){0.f, 0.f, 0.f, 0.f};
#pragma unroll
    for (int ks = 0; ks < 2; ++ks)
#pragma unroll
        for (int rt = 0; rt < 4; ++rt)
#pragma unroll
            for (int ct = 0; ct < 4; ++ct)
                acc[rt][ct] = __builtin_amdgcn_mfma_f32_16x16x32_bf16(afr[ks][rt], bfr[ks][ct],
                                                                      acc[rt][ct], 0, 0, 0);
    int rquad = l >> 4;     // D: col = l&15, row = rquad*4 + reg
#pragma unroll
    for (int ct = 0; ct < 4; ++ct) {
        int col = ct * 16 + colb;
        float bias = bprep[w * 64 + col];
#pragma unroll
        for (int rt = 0; rt < 4; ++rt)
#pragma unroll
            for (int r = 0; r < 4; ++r) {
                int row = row0 + rt * 16 + rquad * 4 + r;
                float val = acc[rt][ct][r] + bias;
                size_t off = (size_t)row * 64 + col;
                if      (w == 0) qb[off] = f2bf(val);
                else if (w == 1) kbuf[off] = val;
                else if (w == 2) vbuf[off] = val;
                else             h[off] += val;     // residual base = h + skip
            }
    }
}

// ---------------- fused attention gather + residual + layernorm ----------------
// grid = 20000: b = bid&7 (XCD affinity), 4 nodes per block (one per wave)
__global__ __launch_bounds__(256, 4) void k_attn_ln(const unsigned short* __restrict__ qb,
                                                    const float* __restrict__ kbuf,
                                                    const float* __restrict__ vbuf,
                                                    const int* __restrict__ rp,
                                                    const int* __restrict__ degv,
                                                    const int* __restrict__ csr,
                                                    const float* __restrict__ lng,
                                                    const float* __restrict__ lnb,
                                                    float* __restrict__ h,
                                                    unsigned short* __restrict__ hb) {
    int b    = blockIdx.x & 7;
    int n    = ((blockIdx.x >> 3) << 2) | __builtin_amdgcn_readfirstlane(threadIdx.x >> 6);
    int lane = threadIdx.x & 63;
    int lg   = lane & 15;       // channel block: channels 4*lg..4*lg+3, head = lg>>2
    int grp  = lane >> 4;       // edge group 0..3
    size_t wid = (size_t)b * NN + n;

    const char* kbase = (const char*)kbuf + (size_t)b * NN * 256;   // wave-uniform
    const char* vbase = (const char*)vbuf + (size_t)b * NN * 256;
    int lgoff = lg * 16;

    ushort4 qu = ((const ushort4*)qb)[wid * 16 + lg];
    float4 q4 = {bf2f(qu.x), bf2f(qu.y), bf2f(qu.z), bf2f(qu.w)};   // already *0.25*log2e

    int e0 = rp[n], deg = degv[n];
    int e1 = e0 + deg;
    float m = -1e30f, den = 0.f;
    float4 av = {0.f, 0.f, 0.f, 0.f};

    int pc0 = csr[e0 + grp], pc1 = csr[e0 + grp + 4];
    for (int e = e0; e < e1; e += 8) {
        int c0 = pc0, c1 = pc1;
        pc0 = csr[e + 8 + grp]; pc1 = csr[e + 12 + grp];    // slack-padded, always safe
        float val0 = (e + grp     < e1) ? 1.f : 0.f;
        float val1 = (e + grp + 4 < e1) ? 1.f : 0.f;
        unsigned o0 = (unsigned)(c0 + lgoff), o1 = (unsigned)(c1 + lgoff);
        float4 ka = *(const float4*)(kbase + o0);
        float4 va = *(const float4*)(vbase + o0);
        float4 kc = *(const float4*)(kbase + o1);
        float4 vc = *(const float4*)(vbase + o1);

        float d0 = ka.x * q4.x + ka.y * q4.y + ka.z * q4.z + ka.w * q4.w;
        float d1 = kc.x * q4.x + kc.y * q4.y + kc.z * q4.z + kc.w * q4.w;
        d0 += __shfl_xor(d0, 1); d0 += __shfl_xor(d0, 2);   // per-head dot (log2 domain)
        d1 += __shfl_xor(d1, 1); d1 += __shfl_xor(d1, 2);

        float dm = fmaxf(d0, d1);
        if (__any(dm > m)) {
            // exact two-step online update (max inflation from padded rows is
            // self-consistent: den and av scale identically, ratio unchanged)
            float nm = fmaxf(m, d0);
            float sc = __builtin_amdgcn_exp2f(m - nm);
            float w0 = val0 * __builtin_amdgcn_exp2f(d0 - nm);
            den = den * sc + w0;
            av.x = av.x * sc + w0 * va.x; av.y = av.y * sc + w0 * va.y;
            av.z = av.z * sc + w0 * va.z; av.w = av.w * sc + w0 * va.w;
            m = nm;
            nm = fmaxf(m, d1);
            sc = __builtin_amdgcn_exp2f(m - nm);
            float w1 = val1 * __builtin_amdgcn_exp2f(d1 - nm);
            den = den * sc + w1;
            av.x = av.x * sc + w1 * vc.x; av.y = av.y * sc + w1 * vc.y;
            av.z = av.z * sc + w1 * vc.z; av.w = av.w * sc + w1 * vc.w;
            m = nm;
        } else {
            // fast path: max unchanged, no rescale
            float w0 = val0 * __builtin_amdgcn_exp2f(d0 - m);
            float w1 = val1 * __builtin_amdgcn_exp2f(d1 - m);
            den += w0 + w1;
            av.x += w0 * va.x + w1 * vc.x; av.y += w0 * va.y + w1 * vc.y;
            av.z += w0 * va.z + w1 * vc.z; av.w += w0 * va.w + w1 * vc.w;
        }
    }

    // merge the 4 edge-groups (flash-style)
#pragma unroll
    for (int off = 16; off <= 32; off <<= 1) {
        float mo  = __shfl_xor(m, off);
        float dno = __shfl_xor(den, off);
        float4 ao = shfl_xor4(av, off);
        float nm = fmaxf(m, mo);
        float s0 = __builtin_amdgcn_exp2f(m - nm), s1 = __builtin_amdgcn_exp2f(mo - nm);
        den = den * s0 + dno * s1;
        av.x = av.x * s0 + ao.x * s1; av.y = av.y * s0 + ao.y * s1;
        av.z = av.z * s0 + ao.z * s1; av.w = av.w * s0 + ao.w * s1;
        m = nm;
    }
    float inv = (den > 0.f) ? __builtin_amdgcn_rcpf(den) : 0.f;

    // residual (h already holds h + skip) + layernorm
    float4 h4 = ((const float4*)h)[wid * 16 + lg];
    float4 x4;
    x4.x = h4.x + av.x * inv; x4.y = h4.y + av.y * inv;
    x4.z = h4.z + av.z * inv; x4.w = h4.w + av.w * inv;

    float s = x4.x + x4.y + x4.z + x4.w;
#pragma unroll
    for (int off = 1; off < 16; off <<= 1) s += __shfl_xor(s, off);
    float mu = s * (1.f / 64.f);
    float4 dx;
    dx.x = x4.x - mu; dx.y = x4.y - mu; dx.z = x4.z - mu; dx.w = x4.w - mu;
    float vs = dx.x * dx.x + dx.y * dx.y + dx.z * dx.z + dx.w * dx.w;
#pragma unroll
    for (int off = 1; off < 16; off <<= 1) vs += __shfl_xor(vs, off);
    float r = __builtin_amdgcn_rsqf(vs * (1.f / 64.f) + 1e-5f);

    float4 g4 = ((const float4*)lng)[lg];
    float4 b4 = ((const float4*)lnb)[lg];
    float4 o4;
    o4.x = dx.x * r * g4.x + b4.x; o4.y = dx.y * r * g4.y + b4.y;
    o4.z = dx.z * r * g4.z + b4.z; o4.w = dx.w * r * g4.w + b4.w;
    if (lane < 16) {
        ((float4*)h)[wid * 16 + lg] = o4;
        ushort4 hu = {f2bf(o4.x), f2bf(o4.y), f2bf(o4.z), f2bf(o4.w)};
        ((ushort4*)hb)[wid * 16 + lg] = hu;
    }
}

// ---------------- output projection ----------------
__global__ __launch_bounds__(256) void k_out(const float* __restrict__ h,
                                             const float* __restrict__ W, const float* __restrict__ bo,
                                             float* __restrict__ out) {
    int idx = blockIdx.x * 256 + threadIdx.x;    // per (b,n)
    if (idx >= BN) return;
    int b = idx / NN, n = idx % NN;
    float a0 = bo[0], a1 = bo[1], a2 = bo[2];
    const float* hr = h + (size_t)idx * 64;
#pragma unroll
    for (int i = 0; i < 64; ++i) {
        float hv = hr[i];
        a0 += hv * W[i * 3 + 0];
        a1 += hv * W[i * 3 + 1];
        a2 += hv * W[i * 3 + 2];
    }
    out[(b * PP + 0) * NN + n] = a0;
    out[(b * PP + 1) * NN + n] = a1;
    out[(b * PP + 2) * NN + n] = a2;
}

extern "C" void kernel_launch(void* const* d_in, const int* in_sizes, int n_in,
                              void* d_out, int out_size, void* d_ws, size_t ws_size,
                              hipStream_t stream) {
    const float* x    = (const float*)d_in[0];
    const int*   ei   = (const int*)  d_in[1];
    const float* inW  = (const float*)d_in[2];
    const float* inb  = (const float*)d_in[3];
    const float* Wq   = (const float*)d_in[4];
    const float* bq   = (const float*)d_in[5];
    const float* Wk   = (const float*)d_in[6];
    const float* bk   = (const float*)d_in[7];
    const float* Wv   = (const float*)d_in[8];
    const float* bv   = (const float*)d_in[9];
    const float* Wsk  = (const float*)d_in[10];
    const float* bsk  = (const float*)d_in[11];
    const float* lng  = (const float*)d_in[12];
    const float* lnb  = (const float*)d_in[13];
    const float* outW = (const float*)d_in[14];
    const float* outb = (const float*)d_in[15];
    float* out = (float*)d_out;

    float* h    = (float*)d_ws;                         // BN*64 f32
    float* kbuf = h    + (size_t)BN * 64;
    float* vbuf = kbuf + (size_t)BN * 64;
    unsigned short* hb = (unsigned short*)(vbuf + (size_t)BN * 64);   // BN*64 bf16
    unsigned short* qb = hb + (size_t)BN * 64;                        // BN*64 bf16
    int* rp      = (int*)(qb + (size_t)BN * 64);
    int* degv    = rp + NN;
    int* cursor  = degv + NN;
    int* csr     = cursor + NN;                          // CSR_CAP entries
    unsigned short* wtb = (unsigned short*)(csr + CSR_CAP);  // LL*4*64*64 bf16
    float* bprep = (float*)(wtb + LL * 4 * 64 * 64);         // LL*4*64 f32

    // CSR build + weight prep (edge list/weights constant across layers/batches)
    hipMemsetAsync(cursor, 0, (NN + CSR_CAP) * sizeof(int), stream);   // cursor + csr
    k_count<<<(EE + 255) / 256, 256, 0, stream>>>(ei, cursor);
    k_scan <<<1, 1024, 0, stream>>>(cursor, rp, degv);
    k_fill <<<(EE + 255) / 256, 256, 0, stream>>>(ei, cursor, csr);
    k_wprep<<<(LL * 4 * 64 * 64 + 255) / 256, 256, 0, stream>>>(Wq, Wk, Wv, Wsk, bq, bk, bv, bsk,
                                                                wtb, bprep);

    k_input_proj<<<(BN * 64 + 255) / 256, 256, 0, stream>>>(x, inW, inb, h, hb);

    for (int l = 0; l < LL; ++l) {
        k_gemm<<<BN / 64, 256, 0, stream>>>(hb, h, wtb + (size_t)l * 4 * 4096,
                                            bprep + (size_t)l * 4 * 64, qb, kbuf, vbuf);
        k_attn_ln<<<BN / 4, 256, 0, stream>>>(qb, kbuf, vbuf, rp, degv, csr,
                                              lng, lnb, h, hb);
    }

    k_out<<<(BN + 255) / 256, 256, 0, stream>>>(h, outW, outb, out);
}